// Round 3
// 389.095 us; speedup vs baseline: 1.1714x; 1.1714x over previous
//
#include <hip/hip_runtime.h>

#define BB 16
#define SS 2048
#define DD 128
#define SCALE 0.08838834764831845f  // 1/sqrt(128)

typedef __attribute__((ext_vector_type(8))) short bf16x8;
typedef __attribute__((ext_vector_type(4))) float f32x4;

__device__ __forceinline__ unsigned short f2bf(float f) {
    union { float f; unsigned int u; } v; v.f = f;
    unsigned int u = v.u;
    return (unsigned short)((u + 0x7fffu + ((u >> 16) & 1u)) >> 16);  // RNE
}

__device__ __forceinline__ void gload16(const void* g, void* l) {
    __builtin_amdgcn_global_load_lds((const __attribute__((address_space(1))) void*)g,
                                     (__attribute__((address_space(3))) void*)l, 16, 0, 0);
}

// ---- pre-pass 1: fp32 -> bf16 contiguous copy (used for Q and K) ----
__global__ __launch_bounds__(256) void cvt_bf16_kernel(const float* __restrict__ src,
                                                       unsigned short* __restrict__ dst) {
    int idx = (blockIdx.x * 256 + threadIdx.x) * 4;
    float4 f = *(const float4*)(src + idx);
    ushort4 o;
    o.x = f2bf(f.x); o.y = f2bf(f.y); o.z = f2bf(f.z); o.w = f2bf(f.w);
    *(ushort4*)(dst + idx) = o;
}

// ---- pre-pass 2: V [B][S][D] fp32 -> Vt [B][D][S] bf16 (transpose) ----
__global__ __launch_bounds__(256) void transpose_v_kernel(const float* __restrict__ v,
                                                          unsigned short* __restrict__ vt) {
    __shared__ unsigned short sT[64 * 132];
    int b = blockIdx.x >> 5;
    int s0 = (blockIdx.x & 31) * 64;
    int tid = threadIdx.x;
#pragma unroll
    for (int rnd = 0; rnd < 8; ++rnd) {
        int slot = rnd * 256 + tid;
        int row = slot >> 5;        // 0..63 (s)
        int c4 = (slot & 31) * 4;   // 0..124 (d)
        float4 f = *(const float4*)(v + (size_t)(b * SS + s0 + row) * DD + c4);
        unsigned short* p = &sT[row * 132 + c4];
        p[0] = f2bf(f.x); p[1] = f2bf(f.y); p[2] = f2bf(f.z); p[3] = f2bf(f.w);
    }
    __syncthreads();
#pragma unroll
    for (int rnd = 0; rnd < 4; ++rnd) {
        int slot = rnd * 256 + tid;
        int d = slot >> 3;          // 0..127
        int k8 = (slot & 7) * 8;    // 0..56
        __align__(16) unsigned short tmp[8];
#pragma unroll
        for (int e = 0; e < 8; ++e) tmp[e] = sT[(k8 + e) * 132 + d];
        *(ushort4*)(vt + (size_t)(b * DD + d) * SS + s0 + k8) = *(ushort4*)&tmp[0];
        *(ushort4*)(vt + (size_t)(b * DD + d) * SS + s0 + k8 + 4) = *(ushort4*)&tmp[4];
    }
}

// ---- main fused attention: one block per (b, 64-row q tile) ----
__global__ __launch_bounds__(256) void attn_kernel(const unsigned short* __restrict__ Qb,
                                                   const unsigned short* __restrict__ Kb,
                                                   const unsigned short* __restrict__ Vt,
                                                   const int* __restrict__ mask,
                                                   float* __restrict__ outO,
                                                   float* __restrict__ outA) {
    // Linear gload_lds-fed buffers. Swizzle: LDS slot (row, chunk') holds global
    // 16B-chunk c = chunk' ^ (row&7); fragment reads apply the same XOR.
    __shared__ unsigned short sA[64 * 128];   // 16KB: p1 K ping / p2 K
    __shared__ unsigned short sB[64 * 128];   // 16KB: p1 K pong / p2 V ping
    __shared__ unsigned short sC[64 * 128];   // 16KB: p2 V pong
    __shared__ unsigned short sQ[64 * 136];   // padded, reg-staged once
    __shared__ unsigned short sP[64 * 72];    // padded (VALU-written)
    __shared__ float sLpart[2][64];
    __shared__ float sLinv[64];

    // XCD-aware swizzle: XCD x handles batches {2x, 2x+1}
    int bi = blockIdx.x;
    int slot = bi >> 3;
    int b = (bi & 7) * 2 + (slot >> 5);
    int qt = slot & 31;

    int tid = threadIdx.x;
    int wave = tid >> 6, lane = tid & 63, lo = lane & 15, hi = lane >> 4;
    const int sw = lo & 7;  // read-side XOR (row&7 == lo&7 for fragment rows)

    const int kq0 = (wave >> 1) * 32;   // wave's k quadrant
    const int qq0 = (wave & 1) * 32;    // wave's q quadrant
    const int dv0 = wave * 32;          // PV: wave owns dv [dv0, dv0+32)

    // ---- stage Q tile once (padded LDS, through regs) ----
    const unsigned short* Qbase = Qb + (size_t)(b * SS + qt * 64) * DD;
#pragma unroll
    for (int rnd = 0; rnd < 4; ++rnd) {
        int sl = rnd * 256 + tid;
        int row = sl >> 4, coff = (sl & 15) * 8;
        *(int4*)&sQ[row * 136 + coff] = *(const int4*)(Qbase + row * DD + coff);
    }

    const char* KB = (const char*)(Kb + (size_t)b * SS * DD);
    const char* VB = (const char*)(Vt + (size_t)b * DD * SS);
    const int* maskB = mask + (size_t)b * SS;

    // per-lane pre-swizzled global source offsets (loop-invariant)
    // K: LDS lane slot -> row = i*16 + RK, chunk' = lane&15, RK = wave*4 + (lane>>4)
    const int RK = wave * 4 + (lane >> 4);
    const unsigned CK = (unsigned)(RK * 256 + (((lane & 15) ^ (RK & 7)) << 4));
    // V: LDS lane slot -> dvrow = i*32 + wave*8 + (lane>>3), chunk' = lane&7
    const unsigned CV = (unsigned)(wave * 32768 + (lane >> 3) * 4096 +
                                   (((lane & 7) ^ (lane >> 3)) << 4));

    auto ISSUE_K = [&](int kt, unsigned short* dst) {
        const char* src = KB + (size_t)kt * 16384 + CK;
        char* d = (char*)dst + wave * 1024;
#pragma unroll
        for (int i = 0; i < 4; ++i)
            gload16(src + i * 4096, d + i * 4096);
    };
    auto ISSUE_V = [&](int kt, unsigned short* dst) {
        const char* src = VB + (size_t)kt * 128 + CV;
        char* d = (char*)dst + wave * 1024;
#pragma unroll
        for (int i = 0; i < 4; ++i)
            gload16(src + (size_t)i * 131072, d + i * 4096);
    };

    // QK^T swapped: acc[ii][jj] -> S^T[k = kq0+ii*16+hi*4+r][q = qq0+jj*16+lo]
    auto QK = [&](const unsigned short* kb, f32x4 (&acc)[2][2]) {
#pragma unroll
        for (int ii = 0; ii < 2; ++ii)
#pragma unroll
            for (int jj = 0; jj < 2; ++jj) acc[ii][jj] = (f32x4){0.f, 0.f, 0.f, 0.f};
        __builtin_amdgcn_s_setprio(1);
#pragma unroll
        for (int ks = 0; ks < 4; ++ks) {
            bf16x8 af[2], bfr[2];
#pragma unroll
            for (int ii = 0; ii < 2; ++ii) {
                int row = kq0 + ii * 16 + lo;
                int ch = (ks * 4 + hi) ^ sw;
                af[ii] = *(const bf16x8*)((const char*)kb + row * 256 + (ch << 4));
            }
#pragma unroll
            for (int jj = 0; jj < 2; ++jj)
                bfr[jj] = *(const bf16x8*)&sQ[(qq0 + jj * 16 + lo) * 136 + ks * 32 + hi * 8];
#pragma unroll
            for (int ii = 0; ii < 2; ++ii)
#pragma unroll
                for (int jj = 0; jj < 2; ++jj)
                    acc[ii][jj] = __builtin_amdgcn_mfma_f32_16x16x32_bf16(af[ii], bfr[jj], acc[ii][jj], 0, 0, 0);
        }
        __builtin_amdgcn_s_setprio(0);
    };

    // ---------------- phase 1: row sums (register-accumulated) ----------------
    float lsum0 = 0.f, lsum1 = 0.f;

    ISSUE_K(0, sA);
#pragma unroll 1
    for (int t = 0; t < 32; ++t) {
        __syncthreads();  // drains own gload K(t); all waves' prev-buffer reads done
        if (t < 31) ISSUE_K(t + 1, (t & 1) ? sA : sB);   // prefetch across barrier
        f32x4 acc[2][2];
        QK((t & 1) ? sB : sA, acc);
        int4 w0 = *(const int4*)(maskB + t * 64 + kq0 + hi * 4);
        int4 w1 = *(const int4*)(maskB + t * 64 + kq0 + 16 + hi * 4);
        float m0[4] = {w0.x ? 1.f : 0.f, w0.y ? 1.f : 0.f, w0.z ? 1.f : 0.f, w0.w ? 1.f : 0.f};
        float m1[4] = {w1.x ? 1.f : 0.f, w1.y ? 1.f : 0.f, w1.z ? 1.f : 0.f, w1.w ? 1.f : 0.f};
#pragma unroll
        for (int r = 0; r < 4; ++r) {
            lsum0 += __expf(acc[0][0][r] * SCALE) * m0[r] + __expf(acc[1][0][r] * SCALE) * m1[r];
            lsum1 += __expf(acc[0][1][r] * SCALE) * m0[r] + __expf(acc[1][1][r] * SCALE) * m1[r];
        }
    }

    // butterfly over hi-groups: lane^16, lane^32
    {
        float v0 = lsum0, v1 = lsum1;
        v0 += __shfl_xor(v0, 16); v0 += __shfl_xor(v0, 32);
        v1 += __shfl_xor(v1, 16); v1 += __shfl_xor(v1, 32);
        if (lane < 16) {
            sLpart[kq0 >> 5][qq0 + lane] = v0;
            sLpart[kq0 >> 5][qq0 + 16 + lane] = v1;
        }
    }
    __syncthreads();
    if (tid < 64) sLinv[tid] = 1.f / (sLpart[0][tid] + sLpart[1][tid]);
    __syncthreads();
    const float linv0 = sLinv[qq0 + lo];
    const float linv1 = sLinv[qq0 + 16 + lo];

    // ---------------- phase 2: recompute S, write attn, O = P V ----------------
    f32x4 oacc[2][4];  // [tj=dv subtile][mi=q subtile]: row = dv, col = q
#pragma unroll
    for (int tj = 0; tj < 2; ++tj)
#pragma unroll
        for (int mi = 0; mi < 4; ++mi) oacc[tj][mi] = (f32x4){0.f, 0.f, 0.f, 0.f};

    float* Abase = outA + (size_t)(b * SS + qt * 64) * SS;

    ISSUE_K(0, sA);
    ISSUE_V(0, sB);
#pragma unroll 1
    for (int t = 0; t < 32; ++t) {
        unsigned short* vcur = (t & 1) ? sC : sB;
        __syncthreads();  // drains K(t), V(t); all waves' prior reads done
        if (t < 31) ISSUE_V(t + 1, (t & 1) ? sB : sC);   // hidden under QK+exp+stores
        f32x4 acc[2][2];
        QK(sA, acc);
        int4 w0 = *(const int4*)(maskB + t * 64 + kq0 + hi * 4);
        int4 w1 = *(const int4*)(maskB + t * 64 + kq0 + 16 + hi * 4);
        float m0[4] = {w0.x ? 1.f : 0.f, w0.y ? 1.f : 0.f, w0.z ? 1.f : 0.f, w0.w ? 1.f : 0.f};
        float m1[4] = {w1.x ? 1.f : 0.f, w1.y ? 1.f : 0.f, w1.z ? 1.f : 0.f, w1.w ? 1.f : 0.f};
#pragma unroll
        for (int jj = 0; jj < 2; ++jj) {
            int q = qq0 + jj * 16 + lo;
            float li = jj ? linv1 : linv0;
#pragma unroll
            for (int ii = 0; ii < 2; ++ii) {
                f32x4 p;
#pragma unroll
                for (int r = 0; r < 4; ++r) {
                    float mv = ii ? m1[r] : m0[r];
                    p[r] = __expf(acc[ii][jj][r] * SCALE) * mv * li;
                }
                int kcol = kq0 + ii * 16 + hi * 4;
                *(f32x4*)(Abase + (size_t)q * SS + t * 64 + kcol) = p;   // float4 store
                ushort4 pb;
                pb.x = f2bf(p[0]); pb.y = f2bf(p[1]); pb.z = f2bf(p[2]); pb.w = f2bf(p[3]);
                *(ushort4*)&sP[q * 72 + kcol] = pb;                       // ds_write_b64
            }
        }
        __syncthreads();  // sP visible; QK readers of sA done
        if (t < 31) ISSUE_K(t + 1, sA);                  // hidden under PV
        // O += V^T-form MFMA: row = dv, col = q
        __builtin_amdgcn_s_setprio(1);
#pragma unroll
        for (int ks = 0; ks < 2; ++ks) {
            bf16x8 pa[4], vb[2];
#pragma unroll
            for (int mi = 0; mi < 4; ++mi)
                pa[mi] = *(const bf16x8*)&sP[(mi * 16 + lo) * 72 + ks * 32 + hi * 8];
#pragma unroll
            for (int tj = 0; tj < 2; ++tj) {
                int rowv = dv0 + tj * 16 + lo;
                int ch = (ks * 4 + hi) ^ sw;   // V rows have 8 chunks; ks<2 so ch in [0,8)
                vb[tj] = *(const bf16x8*)((const char*)vcur + rowv * 128 + (ch << 4));
            }
#pragma unroll
            for (int tj = 0; tj < 2; ++tj)
#pragma unroll
                for (int mi = 0; mi < 4; ++mi)
                    oacc[tj][mi] = __builtin_amdgcn_mfma_f32_16x16x32_bf16(vb[tj], pa[mi], oacc[tj][mi], 0, 0, 0);
        }
        __builtin_amdgcn_s_setprio(0);
    }

    // write O (float4 along dv)
    float* Obase = outO + (size_t)(b * SS + qt * 64) * DD;
#pragma unroll
    for (int tj = 0; tj < 2; ++tj) {
#pragma unroll
        for (int mi = 0; mi < 4; ++mi) {
            int q = mi * 16 + lo;
            int dv = dv0 + tj * 16 + hi * 4;
            *(f32x4*)(Obase + (size_t)q * DD + dv) = oacc[tj][mi];
        }
    }
}

extern "C" void kernel_launch(void* const* d_in, const int* in_sizes, int n_in,
                              void* d_out, int out_size, void* d_ws, size_t ws_size,
                              hipStream_t stream) {
    const float* Q = (const float*)d_in[0];
    const float* K = (const float*)d_in[1];
    const float* V = (const float*)d_in[2];
    const int* mask = (const int*)d_in[3];

    float* outO = (float*)d_out;                          // [B,S,D]
    float* outA = outO + (size_t)BB * SS * DD;            // [B,S,S]

    unsigned short* Qb = (unsigned short*)d_ws;           // bf16 [B,S,D]  8 MiB
    unsigned short* Kb = Qb + (size_t)BB * SS * DD;       // bf16 [B,S,D]  8 MiB
    unsigned short* Vt = Kb + (size_t)BB * SS * DD;       // bf16 [B,D,S]  8 MiB

    int nconv = (BB * SS * DD) / (256 * 4);               // 4096 blocks
    cvt_bf16_kernel<<<nconv, 256, 0, stream>>>(Q, Qb);
    cvt_bf16_kernel<<<nconv, 256, 0, stream>>>(K, Kb);
    transpose_v_kernel<<<BB * (SS / 64), 256, 0, stream>>>(V, Vt);
    attn_kernel<<<BB * (SS / 64), 256, 0, stream>>>(Qb, Kb, Vt, mask, outO, outA);
}